// Round 3
// baseline (1306.937 us; speedup 1.0000x reference)
//
#include <hip/hip_runtime.h>

#define BQ   2
#define QQ   65536
#define HID  256
#define ENC  64
#define NPIX 4096          // 64*64
#define KCONV 576          // ENC*9

using bf16x8 = __bf16 __attribute__((ext_vector_type(8)));
using f32x4  = float  __attribute__((ext_vector_type(4)));

__device__ __forceinline__ unsigned short f2bf(float f){
  unsigned u = __float_as_uint(f);
  u = (u + 0x7fffu + ((u >> 16) & 1u)) >> 16;
  return (unsigned short)u;
}

// sin(2*pi*r) via raw v_fract + v_sin (ISA: v_sin input in revolutions)
__device__ __forceinline__ float sin_rev(float r){
  float f, s;
  asm volatile("v_fract_f32 %0, %1" : "=v"(f) : "v"(r));
  asm volatile("v_sin_f32 %0, %1"   : "=v"(s) : "v"(f));
  return s;
}

// byte offset of bf16 element (row,col) in a [64][256] bf16 LDS tile,
// XOR-swizzled at 16B granularity (kills stride-512B bank conflicts, G4).
__device__ __forceinline__ int xaddr(int row, int col){
  return row*512 + ((((col >> 3) ^ (row & 7)) << 4) | ((col & 7) << 1));
}

// ---------------- prep: weight conversion ---------------------------------
__global__ void prep_kernel(const float* coef_w, const float* freq_w,
                            const float* w0, const float* w1,
                            const float* w2, const float* w3,
                            const float* wo,
                            unsigned short* Wcat, unsigned short* Wmlp,
                            unsigned short* wo_pad){
  int idx = blockIdx.x*256 + threadIdx.x;
  if (idx < 512*KCONV){
    int n = idx / KCONV, k = idx % KCONV;
    int j = k >> 6, cin = k & 63;
    const float* src = (n < 256) ? coef_w : freq_w;
    Wcat[idx] = f2bf(src[(n & 255)*KCONV + cin*9 + j]);
    return;
  }
  int i2 = idx - 512*KCONV;
  if (i2 < 4*65536){
    const float* wl = (i2 < 65536) ? w0 : (i2 < 131072) ? w1
                     : (i2 < 196608) ? w2 : w3;
    Wmlp[i2] = f2bf(wl[i2 & 65535]);
    return;
  }
  int i3 = i2 - 4*65536;
  if (i3 < 16*256){
    int c = i3 >> 8, k = i3 & 255;
    wo_pad[i3] = (c < 3) ? f2bf(wo[c*256 + k]) : (unsigned short)0;
  }
}

// ---------------- enc conv: inp -> fpad bf16 [B][66][66][64] (padded) -----
__global__ __launch_bounds__(256)
void enc_conv_kernel(const float* inp, const float* enc_w, const float* enc_b,
                     unsigned short* fpad){
  __shared__ float wl[ENC*27];
  __shared__ float bl2[ENC];
  __shared__ float tile[256*32];        // 32 KiB, XOR-swizzled [pix][ch32]
  int t = threadIdx.x;
  for (int i = t; i < ENC*27; i += 256) wl[i] = enc_w[i];
  if (t < ENC) bl2[t] = enc_b[t];
  __syncthreads();
  int p  = blockIdx.x*256 + t;
  int b  = p >> 12, yx = p & 4095;
  int y  = yx >> 6, x = yx & 63;
  float v[27];
  #pragma unroll
  for (int c = 0; c < 3; c++)
    #pragma unroll
    for (int dy = 0; dy < 3; dy++)
      #pragma unroll
      for (int dx = 0; dx < 3; dx++){
        int yy = y + dy - 1, xx = x + dx - 1;
        v[c*9 + dy*3 + dx] = (yy >= 0 && yy < 64 && xx >= 0 && xx < 64)
                             ? inp[(b*3 + c)*NPIX + yy*64 + xx] : 0.f;
      }
  int swz_w = (t & 7) << 2;
  for (int h = 0; h < 2; h++){
    for (int oc = 0; oc < 8; oc++){
      float4 a4;
      #pragma unroll
      for (int jj = 0; jj < 4; jj++){
        int o = h*32 + oc*4 + jj;
        float acc = bl2[o];
        #pragma unroll
        for (int k = 0; k < 27; k++) acc += wl[o*27 + k]*v[k];
        ((float*)&a4)[jj] = acc;
      }
      *(float4*)(tile + t*32 + ((oc*4) ^ swz_w)) = a4;
    }
    __syncthreads();
    for (int i = 0; i < 8; i++){
      int lin4 = i*256 + t;
      int pix  = lin4 >> 3, c4 = (lin4 & 7)*4;
      int chx  = c4 ^ ((pix & 7) << 2);
      float4 vv = *(const float4*)(tile + pix*32 + chx);
      int gp = blockIdx.x*256 + pix;
      int gb = gp >> 12, gy = (gp >> 6) & 63, gx = gp & 63;
      ushort4 us;
      us.x = f2bf(vv.x); us.y = f2bf(vv.y); us.z = f2bf(vv.z); us.w = f2bf(vv.w);
      *(ushort4*)(fpad + ((gb*66 + gy + 1)*66 + gx + 1)*64 + h*32 + c4) = us;
    }
    __syncthreads();
  }
}

// ---------------- conv GEMM: coef/freq (no im2col) -------------------------
__global__ __launch_bounds__(256)
void conv_gemm_kernel(const unsigned short* fpad, const unsigned short* Wcat,
                      const float* coef_b, const float* freq_b,
                      float* coefT, float* freqT){
  int wave = threadIdx.x >> 6, lane = threadIdx.x & 63;
  int l16 = lane & 15, g = lane >> 4;
  int tile = blockIdx.x*4 + wave;           // 16384 = 512 pt * 32 nt
  int nt = tile & 31, pt = tile >> 5;
  int gp = pt*16 + l16;                     // pixel handled by this lane
  int b = gp >> 12, y = (gp >> 6) & 63, x = gp & 63;
  const unsigned short* fbase = fpad + ((b*66 + y)*66 + x)*64;
  const unsigned short* Wp = Wcat + (nt*16 + l16)*KCONV + g*8;
  f32x4 acc;
  {
    const float* bsrc = (nt < 16) ? coef_b : freq_b;
    float4 b4 = *(const float4*)(bsrc + ((nt*16) & 255) + g*4);
    acc[0] = b4.x; acc[1] = b4.y; acc[2] = b4.z; acc[3] = b4.w;
  }
  #pragma unroll
  for (int kk = 0; kk < 18; kk++){
    int j = kk >> 1, dy = j/3, dx = j%3;
    bf16x8 bfrag = *(const bf16x8*)(fbase + (dy*66 + dx)*64 + (kk & 1)*32 + g*8);
    bf16x8 afrag = *(const bf16x8*)(Wp + kk*32);
    acc = __builtin_amdgcn_mfma_f32_16x16x32_bf16(afrag, bfrag, acc, 0, 0, 0);
  }
  float4 o4; o4.x = acc[0]; o4.y = acc[1]; o4.z = acc[2]; o4.w = acc[3];
  if (nt < 16) *(float4*)(coefT + gp*256 + nt*16 + g*4)         = o4;
  else         *(float4*)(freqT + gp*256 + (nt - 16)*16 + g*4)  = o4;
}

// ---------------- fused gather/fourier + 4-layer MLP + out layer ----------
// 256 threads (4 waves), 64 rows/block, 32 KiB LDS -> 5 blocks/CU.
__global__ __launch_bounds__(256, 5)
void mlp_kernel(const float* coefT, const float* freqT,
                const float* coord, const float* cell, const float* phase_w,
                const unsigned short* Wmlp,
                const float* b0, const float* b1, const float* b2, const float* b3,
                const unsigned short* wo_pad, const float* bo,
                float* areas, float* pred){
  __shared__ __align__(16) char Xs[64*256*2];   // 32 KiB swizzled bf16 [64][256]
  int t = threadIdx.x;
  int r0 = blockIdx.x*64;
  int wave = t >> 6, lane = t & 63;
  int l16 = lane & 15, g = lane >> 4;
  int half = lane >> 5, l32 = lane & 31;

  // per-lane constant: phase_w pairs p = l32*4 + jj
  float4 pw0 = *(const float4*)(phase_w + 8*l32);
  float4 pw1 = *(const float4*)(phase_w + 8*l32 + 4);
  float coffs = half ? 0.0f : 0.25f;       // sin for half1, cos for half0

  // ---- build X: 16 rows/wave in 2 batches of 8 (pipelined loads) ----
  for (int bi = 0; bi < 2; bi++){
    float2 crd[8], cel[8];
    #pragma unroll
    for (int j = 0; j < 8; j++){
      int gr = r0 + wave*16 + bi*8 + j;
      int bq = gr >> 2;
      crd[j] = *(const float2*)(coord + bq*2);
      cel[j] = *(const float2*)(cell + bq*2);
    }
    int   pix[8]; float rel0[8], rel1[8];
    #pragma unroll
    for (int j = 0; j < 8; j++){
      int gr = r0 + wave*16 + bi*8 + j;
      int s  = gr & 3;
      float vx = (s & 2) ? 1.f : -1.f;
      float vy = (s & 1) ? 1.f : -1.f;
      const float RX = 1.f/64.f;
      float cy = fminf(fmaxf(crd[j].x + vx*RX + 1e-6f, -1.f + 1e-6f), 1.f - 1e-6f);
      float cx = fminf(fmaxf(crd[j].y + vy*RX + 1e-6f, -1.f + 1e-6f), 1.f - 1e-6f);
      int iy = min(max((int)rintf((cy + 1.f)*32.f - 0.5f), 0), 63);
      int ix = min(max((int)rintf((cx + 1.f)*32.f - 0.5f), 0), 63);
      float qy = -1.f + (2*iy + 1)*(1.f/64.f);
      float qx = -1.f + (2*ix + 1)*(1.f/64.f);
      rel0[j] = (crd[j].x - qy)*64.f;
      rel1[j] = (crd[j].y - qx)*64.f;
      if (lane == 0) areas[gr] = fabsf(rel0[j]*rel1[j]) + 1e-9f;
      int b = gr >> 18;                    // bq>>16
      pix[j] = b*NPIX + iy*64 + ix;
    }
    float4 fv0[8], fv1[8], cr4[8];
    #pragma unroll
    for (int j = 0; j < 8; j++){
      const float* fR = freqT + pix[j]*256;
      const float* cR = coefT + pix[j]*256;
      fv0[j] = *(const float4*)(fR + 8*l32);
      fv1[j] = *(const float4*)(fR + 8*l32 + 4);
      cr4[j] = *(const float4*)(cR + half*128 + 4*l32);
    }
    #pragma unroll
    for (int j = 0; j < 8; j++){
      int lr = wave*16 + bi*8 + j;
      float ce0 = cel[j].x*64.f, ce1 = cel[j].y*64.f;
      float q0 = fv0[j].x*rel0[j] + fv0[j].y*rel1[j] + ce0*pw0.x + ce1*pw0.y;
      float q1 = fv0[j].z*rel0[j] + fv0[j].w*rel1[j] + ce0*pw0.z + ce1*pw0.w;
      float q2 = fv1[j].x*rel0[j] + fv1[j].y*rel1[j] + ce0*pw1.x + ce1*pw1.y;
      float q3 = fv1[j].z*rel0[j] + fv1[j].w*rel1[j] + ce0*pw1.z + ce1*pw1.w;
      float v0 = cr4[j].x * sin_rev(q0*0.5f + coffs);
      float v1 = cr4[j].y * sin_rev(q1*0.5f + coffs);
      float v2 = cr4[j].z * sin_rev(q2*0.5f + coffs);
      float v3 = cr4[j].w * sin_rev(q3*0.5f + coffs);
      ushort4 us;
      us.x = f2bf(v0); us.y = f2bf(v1); us.z = f2bf(v2); us.w = f2bf(v3);
      int c0 = half*128 + l32*4;
      *(ushort4*)(Xs + xaddr(lr, c0)) = us;
    }
  }
  __syncthreads();

  const float* const bls[4] = {b0, b1, b2, b3};
  int nbase = wave*64;                  // wave tile: 64 rows x 64 neurons

  #pragma unroll
  for (int l = 0; l < 4; l++){
    const unsigned short* Wl = Wmlp + l*65536;
    f32x4 acc[4][4];
    #pragma unroll
    for (int nt = 0; nt < 4; nt++){
      float4 bv = *(const float4*)(bls[l] + nbase + nt*16 + g*4);
      #pragma unroll
      for (int rt = 0; rt < 4; rt++){
        acc[rt][nt][0] = bv.x; acc[rt][nt][1] = bv.y;
        acc[rt][nt][2] = bv.z; acc[rt][nt][3] = bv.w;
      }
    }
    // double-buffered fragment loads
    bf16x8 xf[2][4], wf[2][4];
    #pragma unroll
    for (int rt = 0; rt < 4; rt++)
      xf[0][rt] = *(const bf16x8*)(Xs + xaddr(rt*16 + l16, g*8));
    #pragma unroll
    for (int nt = 0; nt < 4; nt++)
      wf[0][nt] = *(const bf16x8*)(Wl + (nbase + nt*16 + l16)*256 + g*8);
    #pragma unroll
    for (int kk = 0; kk < 8; kk++){
      int cur = kk & 1, nxt = cur ^ 1;
      if (kk < 7){
        #pragma unroll
        for (int rt = 0; rt < 4; rt++)
          xf[nxt][rt] = *(const bf16x8*)(Xs + xaddr(rt*16 + l16, (kk+1)*32 + g*8));
        #pragma unroll
        for (int nt = 0; nt < 4; nt++)
          wf[nxt][nt] = *(const bf16x8*)(Wl + (nbase + nt*16 + l16)*256 + (kk+1)*32 + g*8);
      }
      #pragma unroll
      for (int nt = 0; nt < 4; nt++)
        #pragma unroll
        for (int rt = 0; rt < 4; rt++)
          acc[rt][nt] = __builtin_amdgcn_mfma_f32_16x16x32_bf16(wf[cur][nt],
                           xf[cur][rt], acc[rt][nt], 0, 0, 0);
    }
    __syncthreads();   // all reads of Xs done -> safe to overwrite
    #pragma unroll
    for (int rt = 0; rt < 4; rt++)
      #pragma unroll
      for (int nt = 0; nt < 4; nt++){
        int row = rt*16 + l16;
        int col = nbase + nt*16 + g*4;
        unsigned lo = (unsigned)f2bf(fmaxf(acc[rt][nt][0], 0.f))
                    | ((unsigned)f2bf(fmaxf(acc[rt][nt][1], 0.f)) << 16);
        unsigned hi = (unsigned)f2bf(fmaxf(acc[rt][nt][2], 0.f))
                    | ((unsigned)f2bf(fmaxf(acc[rt][nt][3], 0.f)) << 16);
        uint2 u; u.x = lo; u.y = hi;
        *(uint2*)(Xs + xaddr(row, col)) = u;
      }
    __syncthreads();
  }

  // ---- output layer: A = wo_pad (16 padded rows), wave w -> 16 rows ----
  {
    f32x4 acc = {0.f, 0.f, 0.f, 0.f};
    #pragma unroll
    for (int kk = 0; kk < 8; kk++){
      bf16x8 wf = *(const bf16x8*)(wo_pad + l16*256 + kk*32 + g*8);
      bf16x8 xf = *(const bf16x8*)(Xs + xaddr(wave*16 + l16, kk*32 + g*8));
      acc = __builtin_amdgcn_mfma_f32_16x16x32_bf16(wf, xf, acc, 0, 0, 0);
    }
    if (g == 0){                         // n = reg (0..3), row = l16
      int row = r0 + wave*16 + l16;
      pred[row*3 + 0] = acc[0] + bo[0];
      pred[row*3 + 1] = acc[1] + bo[1];
      pred[row*3 + 2] = acc[2] + bo[2];
    }
  }
}

// ---------------- combine: area blend + bilinear residual + BN sums -------
__global__ void combine_kernel(const float* pred, const float* areas,
                               const float* coord, const float* inp,
                               float* retbuf, float* bnsums){
  int bq = blockIdx.x*256 + threadIdx.x;   // 0..131071
  int b  = bq >> 16;
  float4 ar = *(const float4*)(areas + bq*4);
  float tot = ar.x + ar.y + ar.z + ar.w;
  float w0_ = ar.w/tot, w1_ = ar.z/tot, w2_ = ar.y/tot, w3_ = ar.x/tot;
  const float* pp = pred + bq*12;
  float r_[3];
  #pragma unroll
  for (int c = 0; c < 3; c++)
    r_[c] = pp[c]*w0_ + pp[3+c]*w1_ + pp[6+c]*w2_ + pp[9+c]*w3_;

  float c0 = coord[bq*2], c1 = coord[bq*2+1];
  float fy = (c0 + 1.f)*32.f - 0.5f, fx = (c1 + 1.f)*32.f - 0.5f;
  float y0f = floorf(fy), x0f = floorf(fx);
  float wy = fy - y0f, wx = fx - x0f;
  int y0 = min(max((int)y0f, 0), 63), y1 = min(max((int)y0f + 1, 0), 63);
  int x0 = min(max((int)x0f, 0), 63), x1 = min(max((int)x0f + 1, 0), 63);
  const float* ib = inp + b*3*NPIX;
  #pragma unroll
  for (int c = 0; c < 3; c++){
    const float* pl = ib + c*NPIX;
    float v00 = pl[y0*64 + x0], v01 = pl[y0*64 + x1];
    float v10 = pl[y1*64 + x0], v11 = pl[y1*64 + x1];
    r_[c] += v00*(1.f-wy)*(1.f-wx) + v01*(1.f-wy)*wx
           + v10*wy*(1.f-wx)       + v11*wy*wx;
    retbuf[bq*3 + c] = r_[c];
  }
  #pragma unroll
  for (int c = 0; c < 3; c++){
    float s = r_[c], ss = r_[c]*r_[c];
    #pragma unroll
    for (int off = 32; off; off >>= 1){
      s  += __shfl_down(s,  off);
      ss += __shfl_down(ss, off);
    }
    if ((threadIdx.x & 63) == 0){
      atomicAdd(&bnsums[c],     s);
      atomicAdd(&bnsums[4 + c], ss);
    }
  }
}

// ---------------- batchnorm normalize -------------------------------------
__global__ void normalize_kernel(const float* retbuf, const float* bnsums,
                                 const float* gamma, const float* beta,
                                 float* out){
  int idx = blockIdx.x*256 + threadIdx.x;
  if (idx >= BQ*QQ*3) return;
  int c = idx % 3;
  const float n = (float)(BQ*QQ);
  float mean = bnsums[c] / n;
  float var  = bnsums[4 + c] / n - mean*mean;
  out[idx] = (retbuf[idx] - mean) * rsqrtf(var + 1e-5f) * gamma[c] + beta[c];
}

extern "C" void kernel_launch(void* const* d_in, const int* in_sizes, int n_in,
                              void* d_out, int out_size, void* d_ws, size_t ws_size,
                              hipStream_t stream){
  const float* inp    = (const float*)d_in[0];
  const float* coord  = (const float*)d_in[1];
  const float* cell   = (const float*)d_in[2];
  const float* enc_w  = (const float*)d_in[3];
  const float* enc_b  = (const float*)d_in[4];
  const float* coef_w = (const float*)d_in[5];
  const float* coef_b = (const float*)d_in[6];
  const float* freq_w = (const float*)d_in[7];
  const float* freq_b = (const float*)d_in[8];
  const float* phase_w= (const float*)d_in[9];
  const float* w0 = (const float*)d_in[10]; const float* b0 = (const float*)d_in[11];
  const float* w1 = (const float*)d_in[12]; const float* b1 = (const float*)d_in[13];
  const float* w2 = (const float*)d_in[14]; const float* b2 = (const float*)d_in[15];
  const float* w3 = (const float*)d_in[16]; const float* b3 = (const float*)d_in[17];
  const float* wo = (const float*)d_in[18]; const float* bo = (const float*)d_in[19];
  const float* gamma = (const float*)d_in[20]; const float* beta = (const float*)d_in[21];

  char* ws = (char*)d_ws;
  unsigned short* fpad   = (unsigned short*)(ws + 0);          // 1,115,136 B
  float*          coefT  = (float*)(ws + 1116160);             // 8 MB
  float*          freqT  = (float*)(ws + 9504768);             // 8 MB
  unsigned short* Wcat   = (unsigned short*)(ws + 17893376);   // 576 KB
  unsigned short* Wmlp   = (unsigned short*)(ws + 18483200);   // 512 KB
  unsigned short* wo_pad = (unsigned short*)(ws + 19007488);   // 8 KB
  float*          areas  = (float*)(ws + 19015680);            // 2 MB
  float*          pred   = (float*)(ws + 21112832);            // 6 MB
  float*          retbuf = (float*)(ws + 27404288);            // 1.5 MB
  float*          bnsums = (float*)(ws + 28977152);            // 32 B
  if (ws_size < 28977184) return;

  hipMemsetAsync(fpad, 0, 1115136, stream);       // zero border
  hipMemsetAsync(bnsums, 0, 32, stream);
  prep_kernel<<<2192, 256, 0, stream>>>(coef_w, freq_w, w0, w1, w2, w3, wo,
                                        Wcat, Wmlp, wo_pad);
  enc_conv_kernel<<<32, 256, 0, stream>>>(inp, enc_w, enc_b, fpad);
  conv_gemm_kernel<<<4096, 256, 0, stream>>>(fpad, Wcat, coef_b, freq_b,
                                             coefT, freqT);
  mlp_kernel<<<8192, 256, 0, stream>>>(coefT, freqT, coord, cell, phase_w, Wmlp,
                                       b0, b1, b2, b3, wo_pad, bo, areas, pred);
  combine_kernel<<<512, 256, 0, stream>>>(pred, areas, coord, inp, retbuf, bnsums);
  normalize_kernel<<<1536, 256, 0, stream>>>(retbuf, bnsums, gamma, beta,
                                             (float*)d_out);
}

// Round 4
// 639.938 us; speedup vs baseline: 2.0423x; 2.0423x over previous
//
#include <hip/hip_runtime.h>

#define BQ   2
#define QQ   65536
#define HID  256
#define ENC  64
#define NPIX 4096          // 64*64
#define KCONV 576          // ENC*9

using bf16x8 = __bf16 __attribute__((ext_vector_type(8)));
using f32x4  = float  __attribute__((ext_vector_type(4)));

__device__ __forceinline__ unsigned short f2bf(float f){
  unsigned u = __float_as_uint(f);
  u = (u + 0x7fffu + ((u >> 16) & 1u)) >> 16;
  return (unsigned short)u;
}

// sin(2*pi*r) via raw v_fract + v_sin (ISA: v_sin input in revolutions)
__device__ __forceinline__ float sin_rev(float r){
  float f, s;
  asm volatile("v_fract_f32 %0, %1" : "=v"(f) : "v"(r));
  asm volatile("v_sin_f32 %0, %1"   : "=v"(s) : "v"(f));
  return s;
}

// byte offset of bf16 element (row,col) in a [128][256] bf16 LDS tile,
// XOR-swizzled at 16B granularity (kills stride-512B bank conflicts, G4).
__device__ __forceinline__ int xaddr(int row, int col){
  return row*512 + ((((col >> 3) ^ (row & 7)) << 4) | ((col & 7) << 1));
}

// ---------------- prep: weight conversion ---------------------------------
__global__ void prep_kernel(const float* coef_w, const float* freq_w,
                            const float* w0, const float* w1,
                            const float* w2, const float* w3,
                            const float* wo,
                            unsigned short* Wcat, unsigned short* Wmlp,
                            unsigned short* wo_pad){
  int idx = blockIdx.x*256 + threadIdx.x;
  if (idx < 512*KCONV){
    int n = idx / KCONV, k = idx % KCONV;
    int j = k >> 6, cin = k & 63;
    const float* src = (n < 256) ? coef_w : freq_w;
    Wcat[idx] = f2bf(src[(n & 255)*KCONV + cin*9 + j]);
    return;
  }
  int i2 = idx - 512*KCONV;
  if (i2 < 4*65536){
    const float* wl = (i2 < 65536) ? w0 : (i2 < 131072) ? w1
                     : (i2 < 196608) ? w2 : w3;
    Wmlp[i2] = f2bf(wl[i2 & 65535]);
    return;
  }
  int i3 = i2 - 4*65536;
  if (i3 < 16*256){
    int c = i3 >> 8, k = i3 & 255;
    wo_pad[i3] = (c < 3) ? f2bf(wo[c*256 + k]) : (unsigned short)0;
  }
}

// ---------------- enc conv: inp -> fpad bf16 [B][66][66][64] (padded) -----
__global__ __launch_bounds__(256)
void enc_conv_kernel(const float* inp, const float* enc_w, const float* enc_b,
                     unsigned short* fpad){
  __shared__ float wl[ENC*27];
  __shared__ float bl2[ENC];
  __shared__ float tile[256*32];        // 32 KiB, XOR-swizzled [pix][ch32]
  int t = threadIdx.x;
  for (int i = t; i < ENC*27; i += 256) wl[i] = enc_w[i];
  if (t < ENC) bl2[t] = enc_b[t];
  __syncthreads();
  int p  = blockIdx.x*256 + t;
  int b  = p >> 12, yx = p & 4095;
  int y  = yx >> 6, x = yx & 63;
  float v[27];
  #pragma unroll
  for (int c = 0; c < 3; c++)
    #pragma unroll
    for (int dy = 0; dy < 3; dy++)
      #pragma unroll
      for (int dx = 0; dx < 3; dx++){
        int yy = y + dy - 1, xx = x + dx - 1;
        v[c*9 + dy*3 + dx] = (yy >= 0 && yy < 64 && xx >= 0 && xx < 64)
                             ? inp[(b*3 + c)*NPIX + yy*64 + xx] : 0.f;
      }
  int swz_w = (t & 7) << 2;
  for (int h = 0; h < 2; h++){
    for (int oc = 0; oc < 8; oc++){
      float4 a4;
      #pragma unroll
      for (int jj = 0; jj < 4; jj++){
        int o = h*32 + oc*4 + jj;
        float acc = bl2[o];
        #pragma unroll
        for (int k = 0; k < 27; k++) acc += wl[o*27 + k]*v[k];
        ((float*)&a4)[jj] = acc;
      }
      *(float4*)(tile + t*32 + ((oc*4) ^ swz_w)) = a4;
    }
    __syncthreads();
    for (int i = 0; i < 8; i++){
      int lin4 = i*256 + t;
      int pix  = lin4 >> 3, c4 = (lin4 & 7)*4;
      int chx  = c4 ^ ((pix & 7) << 2);
      float4 vv = *(const float4*)(tile + pix*32 + chx);
      int gp = blockIdx.x*256 + pix;
      int gb = gp >> 12, gy = (gp >> 6) & 63, gx = gp & 63;
      ushort4 us;
      us.x = f2bf(vv.x); us.y = f2bf(vv.y); us.z = f2bf(vv.z); us.w = f2bf(vv.w);
      *(ushort4*)(fpad + ((gb*66 + gy + 1)*66 + gx + 1)*64 + h*32 + c4) = us;
    }
    __syncthreads();
  }
}

// ---------------- conv GEMM: coef/freq (no im2col) -------------------------
__global__ __launch_bounds__(256)
void conv_gemm_kernel(const unsigned short* fpad, const unsigned short* Wcat,
                      const float* coef_b, const float* freq_b,
                      float* coefT, float* freqT){
  int wave = threadIdx.x >> 6, lane = threadIdx.x & 63;
  int l16 = lane & 15, g = lane >> 4;
  int tile = blockIdx.x*4 + wave;           // 16384 = 512 pt * 32 nt
  int nt = tile & 31, pt = tile >> 5;
  int gp = pt*16 + l16;                     // pixel handled by this lane
  int b = gp >> 12, y = (gp >> 6) & 63, x = gp & 63;
  const unsigned short* fbase = fpad + ((b*66 + y)*66 + x)*64;
  const unsigned short* Wp = Wcat + (nt*16 + l16)*KCONV + g*8;
  f32x4 acc;
  {
    const float* bsrc = (nt < 16) ? coef_b : freq_b;
    float4 b4 = *(const float4*)(bsrc + ((nt*16) & 255) + g*4);
    acc[0] = b4.x; acc[1] = b4.y; acc[2] = b4.z; acc[3] = b4.w;
  }
  #pragma unroll
  for (int kk = 0; kk < 18; kk++){
    int j = kk >> 1, dy = j/3, dx = j%3;
    bf16x8 bfrag = *(const bf16x8*)(fbase + (dy*66 + dx)*64 + (kk & 1)*32 + g*8);
    bf16x8 afrag = *(const bf16x8*)(Wp + kk*32);
    acc = __builtin_amdgcn_mfma_f32_16x16x32_bf16(afrag, bfrag, acc, 0, 0, 0);
  }
  float4 o4; o4.x = acc[0]; o4.y = acc[1]; o4.z = acc[2]; o4.w = acc[3];
  if (nt < 16) *(float4*)(coefT + gp*256 + nt*16 + g*4)         = o4;
  else         *(float4*)(freqT + gp*256 + (nt - 16)*16 + g*4)  = o4;
}

// ---------------- fused gather/fourier + 4-layer MLP + out layer ----------
// 512 threads (8 waves), 128 rows/block, 68 KiB LDS -> 2 blocks/CU.
__global__ __launch_bounds__(512, 4)
void mlp_kernel(const float* coefT, const float* freqT,
                const float* coord, const float* cell, const float* phase_w,
                const unsigned short* Wmlp,
                const float* b0, const float* b1, const float* b2, const float* b3,
                const unsigned short* wo_pad, const float* bo,
                float* areas, float* pred){
  __shared__ __align__(16) char Xs[128*256*2];   // 64 KiB swizzled bf16 [128][256]
  __shared__ __align__(16) float geo[8][16][8];  // 4 KiB row geometry
  int t = threadIdx.x;
  int r0 = blockIdx.x*128;
  int wave = t >> 6, lane = t & 63;
  int l16 = lane & 15, g = lane >> 4;
  int lr0 = wave*16;

  // ---- geometry: lane rr (<16) computes row lr0+rr ----
  if (lane < 16){
    int gr = r0 + lr0 + lane;
    int bq = gr >> 2, s = gr & 3;
    float2 crd = *(const float2*)(coord + bq*2);
    float2 cel = *(const float2*)(cell + bq*2);
    float vx = (s & 2) ? 1.f : -1.f;
    float vy = (s & 1) ? 1.f : -1.f;
    const float RX = 1.f/64.f;
    float cy = fminf(fmaxf(crd.x + vx*RX + 1e-6f, -1.f + 1e-6f), 1.f - 1e-6f);
    float cx = fminf(fmaxf(crd.y + vy*RX + 1e-6f, -1.f + 1e-6f), 1.f - 1e-6f);
    int iy = min(max((int)rintf((cy + 1.f)*32.f - 0.5f), 0), 63);
    int ix = min(max((int)rintf((cx + 1.f)*32.f - 0.5f), 0), 63);
    float qy = -1.f + (2*iy + 1)*RX;
    float qx = -1.f + (2*ix + 1)*RX;
    float rel0 = (crd.x - qy)*64.f;
    float rel1 = (crd.y - qx)*64.f;
    areas[gr] = fabsf(rel0*rel1) + 1e-9f;
    int b = gr >> 18;
    int pix = b*NPIX + iy*64 + ix;
    geo[wave][lane][0] = __int_as_float(pix);
    geo[wave][lane][1] = rel0;
    geo[wave][lane][2] = rel1;
    geo[wave][lane][3] = cel.x*64.f;
    geo[wave][lane][4] = cel.y*64.f;
  }
  // phase_w rows for this lane's 8 pairs (p = 8*l16 + e)
  float4 pw[4];
  #pragma unroll
  for (int j = 0; j < 4; j++)
    pw[j] = *(const float4*)(phase_w + 16*l16 + 4*j);
  __syncthreads();

  // ---- build X: 4 iterations x 4 concurrent rows (16 lanes per row) ----
  #pragma unroll
  for (int it = 0; it < 4; it++){
    int ri = it*4 + g;                    // row index within wave
    int lr = lr0 + ri;
    float4 g4 = *(const float4*)(&geo[wave][ri][0]);
    float ce1 = geo[wave][ri][4];
    int pix = __float_as_int(g4.x);
    float rel0 = g4.y, rel1 = g4.z, ce0 = g4.w;
    const float* fR = freqT + pix*256 + 16*l16;
    const float* cR = coefT + pix*256 + 8*l16;
    float4 fv0 = *(const float4*)(fR);
    float4 fv1 = *(const float4*)(fR + 4);
    float4 fv2 = *(const float4*)(fR + 8);
    float4 fv3 = *(const float4*)(fR + 12);
    float4 cc0 = *(const float4*)(cR);
    float4 cc1 = *(const float4*)(cR + 4);
    float4 cs0 = *(const float4*)(cR + 128);
    float4 cs1 = *(const float4*)(cR + 132);
    unsigned cp[4], sp[4];
    #pragma unroll
    for (int j = 0; j < 4; j++){
      float4 fv = (j==0)?fv0:(j==1)?fv1:(j==2)?fv2:fv3;
      float4 pj = pw[j];
      float ca = (j<2) ? ((j==0)?cc0.x:cc0.z) : ((j==2)?cc1.x:cc1.z);
      float cb = (j<2) ? ((j==0)?cc0.y:cc0.w) : ((j==2)?cc1.y:cc1.w);
      float sa = (j<2) ? ((j==0)?cs0.x:cs0.z) : ((j==2)?cs1.x:cs1.z);
      float sb = (j<2) ? ((j==0)?cs0.y:cs0.w) : ((j==2)?cs1.y:cs1.w);
      float q0 = fv.x*rel0 + fv.y*rel1 + ce0*pj.x + ce1*pj.y;
      float q1 = fv.z*rel0 + fv.w*rel1 + ce0*pj.z + ce1*pj.w;
      float c0 = sin_rev(q0*0.5f + 0.25f) * ca;
      float s0 = sin_rev(q0*0.5f)         * sa;
      float c1 = sin_rev(q1*0.5f + 0.25f) * cb;
      float s1 = sin_rev(q1*0.5f)         * sb;
      cp[j] = (unsigned)f2bf(c0) | ((unsigned)f2bf(c1) << 16);
      sp[j] = (unsigned)f2bf(s0) | ((unsigned)f2bf(s1) << 16);
    }
    uint4 cu; cu.x = cp[0]; cu.y = cp[1]; cu.z = cp[2]; cu.w = cp[3];
    uint4 su; su.x = sp[0]; su.y = sp[1]; su.z = sp[2]; su.w = sp[3];
    *(uint4*)(Xs + xaddr(lr, 8*l16))       = cu;
    *(uint4*)(Xs + xaddr(lr, 128 + 8*l16)) = su;
  }
  __syncthreads();

  const float* const bls[4] = {b0, b1, b2, b3};
  int n0 = wave*32;      // this wave owns output neurons n0..n0+31 each layer

  #pragma unroll
  for (int l = 0; l < 4; l++){
    const unsigned short* Wl = Wmlp + l*65536;
    f32x4 acc[8][2];
    #pragma unroll
    for (int nt = 0; nt < 2; nt++){
      float4 bv = *(const float4*)(bls[l] + n0 + nt*16 + g*4);
      #pragma unroll
      for (int rt = 0; rt < 8; rt++){
        acc[rt][nt][0] = bv.x; acc[rt][nt][1] = bv.y;
        acc[rt][nt][2] = bv.z; acc[rt][nt][3] = bv.w;
      }
    }
    #pragma unroll
    for (int kk = 0; kk < 8; kk++){
      bf16x8 wf0 = *(const bf16x8*)(Wl + (n0 + l16)*256      + kk*32 + g*8);
      bf16x8 wf1 = *(const bf16x8*)(Wl + (n0 + 16 + l16)*256 + kk*32 + g*8);
      #pragma unroll
      for (int rt = 0; rt < 8; rt++){
        bf16x8 xf = *(const bf16x8*)(Xs + xaddr(rt*16 + l16, kk*32 + g*8));
        acc[rt][0] = __builtin_amdgcn_mfma_f32_16x16x32_bf16(wf0, xf, acc[rt][0], 0,0,0);
        acc[rt][1] = __builtin_amdgcn_mfma_f32_16x16x32_bf16(wf1, xf, acc[rt][1], 0,0,0);
      }
    }
    __syncthreads();   // all reads of Xs done -> safe to overwrite
    // D: row(neuron)=g*4+r, col(xrow)=l16 -> packed uint2 per (rt,nt)
    #pragma unroll
    for (int rt = 0; rt < 8; rt++)
      #pragma unroll
      for (int nt = 0; nt < 2; nt++){
        int row = rt*16 + l16;
        int col = n0 + nt*16 + g*4;
        unsigned lo = (unsigned)f2bf(fmaxf(acc[rt][nt][0], 0.f))
                    | ((unsigned)f2bf(fmaxf(acc[rt][nt][1], 0.f)) << 16);
        unsigned hi = (unsigned)f2bf(fmaxf(acc[rt][nt][2], 0.f))
                    | ((unsigned)f2bf(fmaxf(acc[rt][nt][3], 0.f)) << 16);
        uint2 u; u.x = lo; u.y = hi;
        *(uint2*)(Xs + xaddr(row, col)) = u;
      }
    __syncthreads();
  }

  // ---- output layer: A = wo_pad (16 padded rows), wave w -> 16 rows ----
  {
    f32x4 acc = {0.f, 0.f, 0.f, 0.f};
    #pragma unroll
    for (int kk = 0; kk < 8; kk++){
      bf16x8 wf = *(const bf16x8*)(wo_pad + l16*256 + kk*32 + g*8);
      bf16x8 xf = *(const bf16x8*)(Xs + xaddr(wave*16 + l16, kk*32 + g*8));
      acc = __builtin_amdgcn_mfma_f32_16x16x32_bf16(wf, xf, acc, 0, 0, 0);
    }
    if (g == 0){                         // channel = reg (0..3), xrow = l16
      int row = r0 + wave*16 + l16;
      pred[row*3 + 0] = acc[0] + bo[0];
      pred[row*3 + 1] = acc[1] + bo[1];
      pred[row*3 + 2] = acc[2] + bo[2];
    }
  }
}

// ---------------- combine: area blend + bilinear residual + BN sums -------
__global__ void combine_kernel(const float* pred, const float* areas,
                               const float* coord, const float* inp,
                               float* retbuf, float* bnsums){
  int bq = blockIdx.x*256 + threadIdx.x;   // 0..131071
  int b  = bq >> 16;
  float4 ar = *(const float4*)(areas + bq*4);
  float tot = ar.x + ar.y + ar.z + ar.w;
  float w0_ = ar.w/tot, w1_ = ar.z/tot, w2_ = ar.y/tot, w3_ = ar.x/tot;
  const float* pp = pred + bq*12;
  float r_[3];
  #pragma unroll
  for (int c = 0; c < 3; c++)
    r_[c] = pp[c]*w0_ + pp[3+c]*w1_ + pp[6+c]*w2_ + pp[9+c]*w3_;

  float c0 = coord[bq*2], c1 = coord[bq*2+1];
  float fy = (c0 + 1.f)*32.f - 0.5f, fx = (c1 + 1.f)*32.f - 0.5f;
  float y0f = floorf(fy), x0f = floorf(fx);
  float wy = fy - y0f, wx = fx - x0f;
  int y0 = min(max((int)y0f, 0), 63), y1 = min(max((int)y0f + 1, 0), 63);
  int x0 = min(max((int)x0f, 0), 63), x1 = min(max((int)x0f + 1, 0), 63);
  const float* ib = inp + b*3*NPIX;
  #pragma unroll
  for (int c = 0; c < 3; c++){
    const float* pl = ib + c*NPIX;
    float v00 = pl[y0*64 + x0], v01 = pl[y0*64 + x1];
    float v10 = pl[y1*64 + x0], v11 = pl[y1*64 + x1];
    r_[c] += v00*(1.f-wy)*(1.f-wx) + v01*(1.f-wy)*wx
           + v10*wy*(1.f-wx)       + v11*wy*wx;
    retbuf[bq*3 + c] = r_[c];
  }
  #pragma unroll
  for (int c = 0; c < 3; c++){
    float s = r_[c], ss = r_[c]*r_[c];
    #pragma unroll
    for (int off = 32; off; off >>= 1){
      s  += __shfl_down(s,  off);
      ss += __shfl_down(ss, off);
    }
    if ((threadIdx.x & 63) == 0){
      atomicAdd(&bnsums[c],     s);
      atomicAdd(&bnsums[4 + c], ss);
    }
  }
}

// ---------------- batchnorm normalize -------------------------------------
__global__ void normalize_kernel(const float* retbuf, const float* bnsums,
                                 const float* gamma, const float* beta,
                                 float* out){
  int idx = blockIdx.x*256 + threadIdx.x;
  if (idx >= BQ*QQ*3) return;
  int c = idx % 3;
  const float n = (float)(BQ*QQ);
  float mean = bnsums[c] / n;
  float var  = bnsums[4 + c] / n - mean*mean;
  out[idx] = (retbuf[idx] - mean) * rsqrtf(var + 1e-5f) * gamma[c] + beta[c];
}

extern "C" void kernel_launch(void* const* d_in, const int* in_sizes, int n_in,
                              void* d_out, int out_size, void* d_ws, size_t ws_size,
                              hipStream_t stream){
  const float* inp    = (const float*)d_in[0];
  const float* coord  = (const float*)d_in[1];
  const float* cell   = (const float*)d_in[2];
  const float* enc_w  = (const float*)d_in[3];
  const float* enc_b  = (const float*)d_in[4];
  const float* coef_w = (const float*)d_in[5];
  const float* coef_b = (const float*)d_in[6];
  const float* freq_w = (const float*)d_in[7];
  const float* freq_b = (const float*)d_in[8];
  const float* phase_w= (const float*)d_in[9];
  const float* w0 = (const float*)d_in[10]; const float* b0 = (const float*)d_in[11];
  const float* w1 = (const float*)d_in[12]; const float* b1 = (const float*)d_in[13];
  const float* w2 = (const float*)d_in[14]; const float* b2 = (const float*)d_in[15];
  const float* w3 = (const float*)d_in[16]; const float* b3 = (const float*)d_in[17];
  const float* wo = (const float*)d_in[18]; const float* bo = (const float*)d_in[19];
  const float* gamma = (const float*)d_in[20]; const float* beta = (const float*)d_in[21];

  char* ws = (char*)d_ws;
  unsigned short* fpad   = (unsigned short*)(ws + 0);          // 1,115,136 B
  float*          coefT  = (float*)(ws + 1116160);             // 8 MB
  float*          freqT  = (float*)(ws + 9504768);             // 8 MB
  unsigned short* Wcat   = (unsigned short*)(ws + 17893376);   // 576 KB
  unsigned short* Wmlp   = (unsigned short*)(ws + 18483200);   // 512 KB
  unsigned short* wo_pad = (unsigned short*)(ws + 19007488);   // 8 KB
  float*          areas  = (float*)(ws + 19015680);            // 2 MB
  float*          pred   = (float*)(ws + 21112832);            // 6 MB
  float*          retbuf = (float*)(ws + 27404288);            // 1.5 MB
  float*          bnsums = (float*)(ws + 28977152);            // 32 B
  if (ws_size < 28977184) return;

  hipMemsetAsync(fpad, 0, 1115136, stream);       // zero border
  hipMemsetAsync(bnsums, 0, 32, stream);
  prep_kernel<<<2192, 256, 0, stream>>>(coef_w, freq_w, w0, w1, w2, w3, wo,
                                        Wcat, Wmlp, wo_pad);
  enc_conv_kernel<<<32, 256, 0, stream>>>(inp, enc_w, enc_b, fpad);
  conv_gemm_kernel<<<4096, 256, 0, stream>>>(fpad, Wcat, coef_b, freq_b,
                                             coefT, freqT);
  mlp_kernel<<<4096, 512, 0, stream>>>(coefT, freqT, coord, cell, phase_w, Wmlp,
                                       b0, b1, b2, b3, wo_pad, bo, areas, pred);
  combine_kernel<<<512, 256, 0, stream>>>(pred, areas, coord, inp, retbuf, bnsums);
  normalize_kernel<<<1536, 256, 0, stream>>>(retbuf, bnsums, gamma, beta,
                                             (float*)d_out);
}